// Round 1
// baseline (519.969 us; speedup 1.0000x reference)
//
#include <hip/hip_runtime.h>

// ---------- types ----------
typedef float  f32x4 __attribute__((ext_vector_type(4)));
typedef short  s16x8 __attribute__((ext_vector_type(8)));
typedef __bf16 b16x8 __attribute__((ext_vector_type(8)));

#define DEV __device__ __forceinline__

DEV unsigned short f2b(float f) {           // fp32 -> bf16 RNE
  unsigned u = __builtin_bit_cast(unsigned, f);
  u = (u + 0x7FFFu + ((u >> 16) & 1u)) >> 16;
  return (unsigned short)u;
}
DEV float b2f(unsigned short h) {
  unsigned u = ((unsigned)h) << 16;
  return __builtin_bit_cast(float, u);
}
DEV b16x8 ld8(const unsigned short* p) {    // 16B fragment load + reinterpret
  return __builtin_bit_cast(b16x8, *(const s16x8*)p);
}
DEV float sigm(float x) { return __builtin_amdgcn_rcpf(1.f + __expf(-x)); }
DEV float tanh_fast(float x) {
  float e = __expf(2.f * x);                // overflow-safe: e=inf -> 1, e=0 -> -1
  return 1.f - 2.f * __builtin_amdgcn_rcpf(e + 1.f);
}
DEV void async16(const unsigned short* g, unsigned short* l) {
  __builtin_amdgcn_global_load_lds(
      (const __attribute__((address_space(1))) unsigned int*)g,
      (__attribute__((address_space(3))) unsigned int*)l, 16, 0, 0);
}
DEV f32x4 mfma_bf16(b16x8 a, b16x8 b, f32x4 c) {
  return __builtin_amdgcn_mfma_f32_16x16x32_bf16(a, b, c, 0, 0, 0);
}

// ---------- prep: fp32 weights -> bf16 (+K padding, +Whh|Wih fusion) ----------
struct PrepArgs {
  const float* whh[2];
  const float* wih[2];
  unsigned short* waug[2];          // [768][288]
  const float* src[2][4];           // fc1..fc4 weights per branch
  unsigned short* dst[2][4];
};

__global__ __launch_bounds__(256) void prep_kernel(PrepArgs p) {
  const int job = blockIdx.y;
  const int i0 = blockIdx.x * 256 + threadIdx.x;
  const int stride = gridDim.x * 256;
  if (job < 2) {                      // Waug = [Whh(256) | Wih(15) | zeros(17)]
    const float* whh = p.whh[job];
    const float* wih = p.wih[job];
    unsigned short* dst = p.waug[job];
    for (int idx = i0; idx < 768 * 288; idx += stride) {
      int j = idx / 288, k = idx - j * 288;
      float v = 0.f;
      if (k < 256)      v = whh[j * 256 + k];
      else if (k < 271) v = wih[j * 15 + (k - 256)];
      dst[idx] = f2b(v);
    }
  } else {
    const int jj = job - 2, br = jj >> 2, ly = jj & 3;
    const int rowsA[4] = {1024, 1024, 512, 256};
    const int scA[4]   = {272, 1024, 1024, 512};
    const int dcA[4]   = {288, 1024, 1024, 512};
    const float* src = p.src[br][ly];
    unsigned short* dst = p.dst[br][ly];
    const int sc = scA[ly], dc = dcA[ly], tot = rowsA[ly] * dc;
    for (int idx = i0; idx < tot; idx += stride) {
      int r = idx / dc, c = idx - r * dc;
      float v = (c < sc) ? src[r * sc + c] : 0.f;
      dst[idx] = f2b(v);
    }
  }
}

// ---------- persistent fused GRU ----------
// grid 256 blocks x 512 threads. block = (gru g, 16 batch rows).
// Per step: acc = bih ; +state_t@Wih (aug kstep, done first, i_n snapshotted)
//           ; +bhh ; +h@Whh (8 ksteps). Elementwise gates wave-local in regs.
// Waug ksteps {8,0,1,2} register-resident per wave (96 VGPRs), {3..7} L2-streamed.
__global__ __launch_bounds__(512, 2) void gru_kernel(
    const float* __restrict__ state, const float* __restrict__ action,
    const int* __restrict__ lengths,
    const unsigned short* __restrict__ waug0, const unsigned short* __restrict__ waug1,
    const float* __restrict__ bih0, const float* __restrict__ bhh0,
    const float* __restrict__ bih1, const float* __restrict__ bhh1,
    unsigned short* __restrict__ x0, unsigned short* __restrict__ x1) {
  const int tid = threadIdx.x;
  const int lane = tid & 63, w = tid >> 6;
  const int l15 = lane & 15, q = lane >> 4;
  const int g = blockIdx.x & 1;
  const int r0 = (blockIdx.x >> 1) * 16;

  const unsigned short* Waug = g ? waug1 : waug0;
  const float* bih = g ? bih1 : bih0;
  const float* bhh = g ? bhh1 : bhh0;
  unsigned short* xout = g ? x1 : x0;

  // Hb row = batch row, cols 0..255 = h (bf16), 256..287 = [state_t | 0] aug.
  // row stride 296 -> 2-way-max bank aliasing on b128 reads (free).
  __shared__ unsigned short Hb[16 * 296];
  __shared__ int lenS[16];
  __shared__ int mlS;

  for (int i = tid; i < 16 * 296; i += 512) Hb[i] = 0;
  if (tid < 16) lenS[tid] = lengths[r0 + tid];
  __syncthreads();
  if (tid == 0) {
    int m = 1;
    for (int i = 0; i < 16; i++) m = lenS[i] > m ? lenS[i] : m;
    mlS = m;
  }
  __syncthreads();
  const int maxlen = mlS;
  int len4[4];
#pragma unroll
  for (int r = 0; r < 4; r++) len4[r] = lenS[q * 4 + r];

  // wave-local tile columns: r:{c,c+16} z:{256+c,..} n:{512+c,..} with c=32w
  int c0[6];
  c0[0] = 32 * w;       c0[1] = 32 * w + 16;
  c0[2] = 256 + 32 * w; c0[3] = 256 + 32 * w + 16;
  c0[4] = 512 + 32 * w; c0[5] = 512 + 32 * w + 16;

  float brz[4];
#pragma unroll
  for (int i = 0; i < 4; i++) brz[i] = bih[c0[i] + l15] + bhh[c0[i] + l15];
  float bnI[2] = {bih[c0[4] + l15], bih[c0[5] + l15]};
  float bnH[2] = {bhh[c0[4] + l15], bhh[c0[5] + l15]};

  const unsigned short* bp[6];
#pragma unroll
  for (int i = 0; i < 6; i++) bp[i] = Waug + (size_t)(c0[i] + l15) * 288 + q * 8;

  // register-resident B-fragments for ksteps {8,0,1,2}
  b16x8 wres[6][4];
  const int ksmap[4] = {8, 0, 1, 2};
#pragma unroll
  for (int i = 0; i < 6; i++)
#pragma unroll
    for (int j = 0; j < 4; j++) wres[i][j] = ld8(bp[i] + ksmap[j] * 32);

  float hold[2][4] = {{0, 0, 0, 0}, {0, 0, 0, 0}};  // fp32 recurrent carry

  // state staging: threads 0..239 each own (row, d)
  const int srow = tid / 15, sd = tid - srow * 15;
  const float* sp = state + (size_t)(r0 + (srow & 15)) * 960 + sd;  // [b][t][d], 960=T*D

  for (int t = 0; t < maxlen; ++t) {
    if (tid < 240) Hb[srow * 296 + 256 + sd] = f2b(sp[t * 15]);
    __syncthreads();  // staging + prev elementwise visible before MFMA reads

    f32x4 acc[6];
#pragma unroll
    for (int i = 0; i < 4; i++) acc[i] = f32x4{brz[i], brz[i], brz[i], brz[i]};
    acc[4] = f32x4{bnI[0], bnI[0], bnI[0], bnI[0]};
    acc[5] = f32x4{bnI[1], bnI[1], bnI[1], bnI[1]};

    // aug kstep first: acc = bih + state@Wih  (== i gates)
    b16x8 a8 = ld8(&Hb[l15 * 296 + 8 * 32 + q * 8]);
#pragma unroll
    for (int i = 0; i < 6; i++) acc[i] = mfma_bf16(a8, wres[i][0], acc[i]);
    f32x4 giN0 = acc[4], giN1 = acc[5];  // snapshot i_n
    acc[4] = acc[4] + bnH[0];
    acc[5] = acc[5] + bnH[1];

    // resident ksteps 0..2
#pragma unroll
    for (int j = 1; j < 4; j++) {
      b16x8 a = ld8(&Hb[l15 * 296 + (j - 1) * 32 + q * 8]);
#pragma unroll
      for (int i = 0; i < 6; i++) acc[i] = mfma_bf16(a, wres[i][j], acc[i]);
    }

    // streamed ksteps 3..7 (L2-hit), 1-deep prefetch
    b16x8 bs[6];
#pragma unroll
    for (int i = 0; i < 6; i++) bs[i] = ld8(bp[i] + 3 * 32);
#pragma unroll
    for (int ks = 3; ks <= 7; ++ks) {
      b16x8 cur[6];
#pragma unroll
      for (int i = 0; i < 6; i++) cur[i] = bs[i];
      if (ks < 7) {
#pragma unroll
        for (int i = 0; i < 6; i++) bs[i] = ld8(bp[i] + (ks + 1) * 32);
      }
      b16x8 a = ld8(&Hb[l15 * 296 + ks * 32 + q * 8]);
#pragma unroll
      for (int i = 0; i < 6; i++) acc[i] = mfma_bf16(a, cur[i], acc[i]);
    }

    __syncthreads();  // all waves done reading Hb h-cols before we overwrite

    // wave-local elementwise: acc element = (row=q*4+reg, col=c0[i]+l15)
#pragma unroll
    for (int i = 0; i < 2; i++) {
      const int c = 32 * w + 16 * i + l15;
#pragma unroll
      for (int rg = 0; rg < 4; rg++) {
        const int row = q * 4 + rg;
        float r = sigm(acc[0 + i][rg]);
        float z = sigm(acc[2 + i][rg]);
        float inn = i ? giN1[rg] : giN0[rg];
        float hn = acc[4 + i][rg] - inn;       // h_n = g_n - i_n
        float nn = tanh_fast(inn + r * hn);
        float hv = (1.f - z) * nn + z * hold[i][rg];
        hv = (t < len4[rg]) ? hv : hold[i][rg];  // ragged freeze
        hold[i][rg] = hv;
        Hb[row * 296 + c] = f2b(hv);
      }
    }
    // next iteration's leading barrier orders these writes vs. MFMA reads
  }

  // emit x = [state[:,0,:], action, h, 0-pad] as bf16 [16][288]
#pragma unroll
  for (int i = 0; i < 2; i++) {
    const int c = 32 * w + 16 * i + l15;
#pragma unroll
    for (int rg = 0; rg < 4; rg++) {
      const int row = q * 4 + rg;
      xout[(size_t)(r0 + row) * 288 + 16 + c] = f2b(hold[i][rg]);
    }
  }
  {
    const int row = tid >> 5, cc = tid & 31;  // 512 threads cover 16x32
    float v; int col;
    if (cc < 15)       { v = state[(size_t)(r0 + row) * 960 + cc]; col = cc; }
    else if (cc == 15) { v = action[r0 + row]; col = 15; }
    else               { v = 0.f; col = 256 + cc; }  // 272..287 zero pad
    xout[(size_t)(r0 + row) * 288 + col] = f2b(v);
  }
}

// ---------- bf16 GEMM: Y = relu(A @ W^T + b), m97-style staging ----------
// BM=128 fixed, BN template (128 or 64). 256 thr = 4 waves (2x2 of 64 x BN/2).
template <int BN>
__global__ __launch_bounds__(256, 2) void gemm_bias_relu(
    const unsigned short* __restrict__ A0, const unsigned short* __restrict__ A1,
    const unsigned short* __restrict__ W0, const unsigned short* __restrict__ W1,
    const float* __restrict__ b0, const float* __restrict__ b1,
    unsigned short* __restrict__ Y0, unsigned short* __restrict__ Y1,
    int N, int K) {
  const unsigned short* A = blockIdx.z ? A1 : A0;
  const unsigned short* W = blockIdx.z ? W1 : W0;
  const float* bias = blockIdx.z ? b1 : b0;
  unsigned short* Y = blockIdx.z ? Y1 : Y0;

  constexpr int NT = BN / 32;
  const int tid = threadIdx.x;
  const int lane = tid & 63, wid = tid >> 6;
  const int wm = wid >> 1, wn = wid & 1;
  const int l15 = lane & 15, q = lane >> 4;
  const int m0 = blockIdx.x * 128, n0 = blockIdx.y * BN;

  __shared__ unsigned short As[128 * 32];
  __shared__ unsigned short Bs[BN * 32];

  f32x4 acc[4][NT];
#pragma unroll
  for (int mi = 0; mi < 4; mi++)
#pragma unroll
    for (int ni = 0; ni < NT; ni++) acc[mi][ni] = f32x4{0.f, 0.f, 0.f, 0.f};

  const int srow = tid >> 2, scol = (tid & 3) * 8;
  const unsigned short* aP0 = A + (size_t)(m0 + srow) * K + scol;
  const unsigned short* aP1 = A + (size_t)(m0 + 64 + srow) * K + scol;
  const unsigned short* bP0 = W + (size_t)(n0 + srow) * K + scol;
  const unsigned short* bP1 = W + (size_t)(n0 + (BN == 128 ? 64 : 0) + srow) * K + scol;

  for (int k0 = 0; k0 < K; k0 += 32) {
    async16(aP0 + k0, &As[(size_t)tid * 8]);
    async16(aP1 + k0, &As[2048 + (size_t)tid * 8]);
    async16(bP0 + k0, &Bs[(size_t)tid * 8]);
    if constexpr (BN == 128) async16(bP1 + k0, &Bs[2048 + (size_t)tid * 8]);
    __syncthreads();

    b16x8 af[4], bf[NT];
#pragma unroll
    for (int mi = 0; mi < 4; mi++)
      af[mi] = ld8(&As[(wm * 64 + mi * 16 + l15) * 32 + q * 8]);
#pragma unroll
    for (int ni = 0; ni < NT; ni++)
      bf[ni] = ld8(&Bs[(wn * (BN / 2) + ni * 16 + l15) * 32 + q * 8]);
#pragma unroll
    for (int mi = 0; mi < 4; mi++)
#pragma unroll
      for (int ni = 0; ni < NT; ni++)
        acc[mi][ni] = mfma_bf16(af[mi], bf[ni], acc[mi][ni]);
    __syncthreads();
  }

#pragma unroll
  for (int ni = 0; ni < NT; ni++) {
    const int col = n0 + wn * (BN / 2) + ni * 16 + l15;
    const float bv = bias[col];
#pragma unroll
    for (int mi = 0; mi < 4; mi++) {
      const int rbase = m0 + wm * 64 + mi * 16 + q * 4;
#pragma unroll
      for (int rg = 0; rg < 4; rg++) {
        float v = acc[mi][ni][rg] + bv;
        v = fmaxf(v, 0.f);
        Y[(size_t)(rbase + rg) * N + col] = f2b(v);
      }
    }
  }
}

// ---------- final q-row: out[b] = y4[b,:] . qw + qb ----------
__global__ __launch_bounds__(256) void qdot(
    const unsigned short* __restrict__ y0, const unsigned short* __restrict__ y1,
    const float* __restrict__ qw0, const float* __restrict__ qb0,
    const float* __restrict__ qw1, const float* __restrict__ qb1,
    float* __restrict__ out) {
  const int lane = threadIdx.x & 63, wid = threadIdx.x >> 6;
  const int row = blockIdx.x * 4 + wid;
  const int br = blockIdx.y;
  const unsigned short* y = br ? y1 : y0;
  const float* qw = br ? qw1 : qw0;
  const float* qb = br ? qb1 : qb0;
  const unsigned short* p = y + (size_t)row * 256 + lane * 4;
  float s = 0.f;
#pragma unroll
  for (int j = 0; j < 4; j++) s += b2f(p[j]) * qw[lane * 4 + j];
#pragma unroll
  for (int off = 32; off > 0; off >>= 1) s += __shfl_down(s, off);
  if (lane == 0) out[br * 2048 + row] = s + qb[0];
}

// ---------- host ----------
extern "C" void kernel_launch(void* const* d_in, const int* in_sizes, int n_in,
                              void* d_out, int out_size, void* d_ws, size_t ws_size,
                              hipStream_t stream) {
  const float* state   = (const float*)d_in[0];
  const float* action  = (const float*)d_in[1];
  const int*   lengths = (const int*)d_in[2];
  const float* g_wih[2] = {(const float*)d_in[3], (const float*)d_in[17]};
  const float* g_whh[2] = {(const float*)d_in[4], (const float*)d_in[18]};
  const float* g_bih[2] = {(const float*)d_in[5], (const float*)d_in[19]};
  const float* g_bhh[2] = {(const float*)d_in[6], (const float*)d_in[20]};
  const float* fcw[2][4] = {
      {(const float*)d_in[7], (const float*)d_in[9], (const float*)d_in[11], (const float*)d_in[13]},
      {(const float*)d_in[21], (const float*)d_in[23], (const float*)d_in[25], (const float*)d_in[27]}};
  const float* fcb[2][4] = {
      {(const float*)d_in[8], (const float*)d_in[10], (const float*)d_in[12], (const float*)d_in[14]},
      {(const float*)d_in[22], (const float*)d_in[24], (const float*)d_in[26], (const float*)d_in[28]}};
  const float* qw[2] = {(const float*)d_in[15], (const float*)d_in[29]};
  const float* qb[2] = {(const float*)d_in[16], (const float*)d_in[30]};
  float* out = (float*)d_out;

  uintptr_t base = (uintptr_t)d_ws;
  auto alloc = [&](size_t bytes) -> unsigned short* {
    void* p = (void*)base;
    base += (bytes + 255) & ~(size_t)255;
    return (unsigned short*)p;
  };
  unsigned short *waug[2], *w1b[2], *w2b[2], *w3b[2], *w4b[2], *xb[2], *yA[2], *yB[2];
  for (int g = 0; g < 2; g++) waug[g] = alloc(768 * 288 * 2);
  for (int g = 0; g < 2; g++) w1b[g] = alloc(1024 * 288 * 2);
  for (int g = 0; g < 2; g++) w2b[g] = alloc(1024 * 1024 * 2);
  for (int g = 0; g < 2; g++) w3b[g] = alloc(512 * 1024 * 2);
  for (int g = 0; g < 2; g++) w4b[g] = alloc(256 * 512 * 2);
  for (int g = 0; g < 2; g++) xb[g] = alloc(2048 * 288 * 2);
  for (int g = 0; g < 2; g++) yA[g] = alloc(2048 * 1024 * 2);  // fc1 out; fc3 out reuses
  for (int g = 0; g < 2; g++) yB[g] = alloc(2048 * 1024 * 2);  // fc2 out; fc4 out reuses
  (void)ws_size; (void)in_sizes; (void)n_in; (void)out_size;   // ~28 MB total

  PrepArgs pa;
  for (int g = 0; g < 2; g++) {
    pa.whh[g] = g_whh[g]; pa.wih[g] = g_wih[g]; pa.waug[g] = waug[g];
    pa.src[g][0] = fcw[g][0]; pa.dst[g][0] = w1b[g];
    pa.src[g][1] = fcw[g][1]; pa.dst[g][1] = w2b[g];
    pa.src[g][2] = fcw[g][2]; pa.dst[g][2] = w3b[g];
    pa.src[g][3] = fcw[g][3]; pa.dst[g][3] = w4b[g];
  }
  prep_kernel<<<dim3(64, 10), 256, 0, stream>>>(pa);

  gru_kernel<<<dim3(256), dim3(512), 0, stream>>>(
      state, action, lengths, waug[0], waug[1],
      g_bih[0], g_bhh[0], g_bih[1], g_bhh[1], xb[0], xb[1]);

  gemm_bias_relu<128><<<dim3(16, 8, 2), 256, 0, stream>>>(
      xb[0], xb[1], w1b[0], w1b[1], fcb[0][0], fcb[1][0], yA[0], yA[1], 1024, 288);
  gemm_bias_relu<128><<<dim3(16, 8, 2), 256, 0, stream>>>(
      yA[0], yA[1], w2b[0], w2b[1], fcb[0][1], fcb[1][1], yB[0], yB[1], 1024, 1024);
  gemm_bias_relu<64><<<dim3(16, 8, 2), 256, 0, stream>>>(
      yB[0], yB[1], w3b[0], w3b[1], fcb[0][2], fcb[1][2], yA[0], yA[1], 512, 1024);
  gemm_bias_relu<64><<<dim3(16, 4, 2), 256, 0, stream>>>(
      yA[0], yA[1], w4b[0], w4b[1], fcb[0][3], fcb[1][3], yB[0], yB[1], 256, 512);

  qdot<<<dim3(512, 2), 256, 0, stream>>>(yB[0], yB[1], qw[0], qb[0], qw[1], qb[1], out);
}

// Round 2
// 355.914 us; speedup vs baseline: 1.4609x; 1.4609x over previous
//
#include <hip/hip_runtime.h>

// ---------- types ----------
typedef float  f32x4 __attribute__((ext_vector_type(4)));
typedef short  s16x8 __attribute__((ext_vector_type(8)));
typedef __bf16 b16x8 __attribute__((ext_vector_type(8)));

#define DEV __device__ __forceinline__

DEV unsigned short f2b(float f) {           // fp32 -> bf16 RNE
  unsigned u = __builtin_bit_cast(unsigned, f);
  u = (u + 0x7FFFu + ((u >> 16) & 1u)) >> 16;
  return (unsigned short)u;
}
DEV float b2f(unsigned short h) {
  unsigned u = ((unsigned)h) << 16;
  return __builtin_bit_cast(float, u);
}
DEV b16x8 ld8(const unsigned short* p) {    // 16B fragment load + reinterpret
  return __builtin_bit_cast(b16x8, *(const s16x8*)p);
}
DEV float sigm(float x) { return __builtin_amdgcn_rcpf(1.f + __expf(-x)); }
DEV float tanh_fast(float x) {
  float e = __expf(2.f * x);                // overflow-safe: e=inf -> 1, e=0 -> -1
  return 1.f - 2.f * __builtin_amdgcn_rcpf(e + 1.f);
}
DEV void async16(const unsigned short* g, unsigned short* l) {
  __builtin_amdgcn_global_load_lds(
      (const __attribute__((address_space(1))) unsigned int*)g,
      (__attribute__((address_space(3))) unsigned int*)l, 16, 0, 0);
}
DEV f32x4 mfma_bf16(b16x8 a, b16x8 b, f32x4 c) {
  return __builtin_amdgcn_mfma_f32_16x16x32_bf16(a, b, c, 0, 0, 0);
}

// ---------- prep: build Waug [768][288] bf16 = [Whh | Wih | bias@271 | 0] ----------
// bias col 271: r,z rows get bih+bhh (full bias); n rows get bih only (so the
// post-aug snapshot equals i_n exactly); bhh_n is added in-kernel after snapshot.
__global__ __launch_bounds__(256) void prep_waug(
    const float* __restrict__ whh0, const float* __restrict__ wih0,
    const float* __restrict__ bih0, const float* __restrict__ bhh0,
    const float* __restrict__ whh1, const float* __restrict__ wih1,
    const float* __restrict__ bih1, const float* __restrict__ bhh1,
    unsigned short* __restrict__ dst0, unsigned short* __restrict__ dst1) {
  const int g = blockIdx.y;
  const float* whh = g ? whh1 : whh0;
  const float* wih = g ? wih1 : wih0;
  const float* bih = g ? bih1 : bih0;
  const float* bhh = g ? bhh1 : bhh0;
  unsigned short* dst = g ? dst1 : dst0;
  const int i0 = blockIdx.x * 256 + threadIdx.x;
  const int stride = gridDim.x * 256;
  for (int idx = i0; idx < 768 * 288; idx += stride) {
    int j = idx / 288, k = idx - j * 288;
    float v = 0.f;
    if (k < 256)       v = whh[j * 256 + k];
    else if (k < 271)  v = wih[j * 15 + (k - 256)];
    else if (k == 271) v = (j < 512) ? (bih[j] + bhh[j]) : bih[j];
    dst[idx] = f2b(v);
  }
}

// ---------- persistent fused GRU, weights fully on-chip resident ----------
// 256 blocks x 512 thr; block = (gru g, 16 batch rows).
// Waug ksteps {0..5, aug} register-resident (168 VGPR/lane);
// ksteps {6,7} in per-lane LDS arena (96 KB, conflict-free b128);
// full state tile pre-converted to A-fragment layout in LDS (32 KB).
#define GRU_LDS_BYTES 140672
__global__ __launch_bounds__(512) void gru_kernel(
    const float* __restrict__ state, const float* __restrict__ action,
    const int* __restrict__ lengths,
    const unsigned short* __restrict__ waug0, const unsigned short* __restrict__ waug1,
    const float* __restrict__ bhh0, const float* __restrict__ bhh1,
    unsigned short* __restrict__ x0, unsigned short* __restrict__ x1) {
  extern __shared__ char smem[];
  unsigned short* W67L = (unsigned short*)smem;             // 96 KB arena
  unsigned short* SgL  = (unsigned short*)(smem + 98304);   // 32 KB state frags
  unsigned short* Hb   = (unsigned short*)(smem + 131072);  // 16 x 296 halves
  int* lenS = (int*)(smem + 140544);
  int* mlS  = (int*)(smem + 140608);
  float* tmpF = (float*)smem;                               // phase-a overlay on W67L

  const int tid = threadIdx.x;
  const int lane = tid & 63, w = tid >> 6;
  const int l15 = lane & 15, q = lane >> 4;
  const int g = blockIdx.x & 1;
  const int r0 = (blockIdx.x >> 1) * 16;

  const unsigned short* Waug = g ? waug1 : waug0;
  const float* bhh = g ? bhh1 : bhh0;
  unsigned short* xout = g ? x1 : x0;

  // ---- phase a: stage state tile fp32 -> LDS (coalesced), lens, Hb zero ----
  {
    const float4* src = (const float4*)(state + (size_t)r0 * 960);
    float4* dstv = (float4*)tmpF;
    for (int i = tid; i < 3840; i += 512) dstv[i] = src[i];  // 16 rows x 960 f
  }
  for (int i = tid; i < 16 * 296; i += 512) Hb[i] = 0;
  if (tid < 16) lenS[tid] = lengths[r0 + tid];
  __syncthreads();

  if (tid == 0) {
    int m = 1;
    for (int i = 0; i < 16; i++) m = lenS[i] > m ? lenS[i] : m;
    *mlS = m;
  }

  // ---- phase b: build SgL[t][L=0..31] = aug A-fragment (state 15 | 1.0 | 0) ----
  // aug MFMA A layout: lane(q,l15): m=l15 (batch row), k=8q+j; only q<2 nonzero.
  for (int s = tid; s < 64 * 32; s += 512) {
    const int t = s >> 5, L = s & 31;
    const int q2 = L >> 4, r = L & 15;
    s16x8 h;
#pragma unroll
    for (int j = 0; j < 8; j++) {
      const int k = q2 * 8 + j;
      float v = (k < 15) ? tmpF[r * 960 + t * 15 + k] : (k == 15 ? 1.0f : 0.f);
      h[j] = (short)f2b(v);
    }
    *(s16x8*)(SgL + (size_t)s * 8) = h;
  }
  __syncthreads();  // tmpF dead; W67L arena may now be filled

  // ---- phase c: load resident weights, fill W67L arena ----
  int c0[6];
  c0[0] = 32 * w;       c0[1] = 32 * w + 16;
  c0[2] = 256 + 32 * w; c0[3] = 256 + 32 * w + 16;
  c0[4] = 512 + 32 * w; c0[5] = 512 + 32 * w + 16;

  b16x8 wres[6][6];   // h ksteps 0..5
  b16x8 waugf[6];     // aug kstep (k 256..287, bias folded at 271)
#pragma unroll
  for (int i = 0; i < 6; i++) {
    const unsigned short* bpi = Waug + (size_t)(c0[i] + l15) * 288 + q * 8;
#pragma unroll
    for (int j = 0; j < 6; j++) wres[i][j] = ld8(bpi + j * 32);
    waugf[i] = ld8(bpi + 256);
#pragma unroll
    for (int ks2 = 0; ks2 < 2; ks2++) {
      b16x8 v = ld8(bpi + (6 + ks2) * 32);
      *(s16x8*)(W67L + (size_t)(ks2 * 6 + i) * 4096 + tid * 8) =
          __builtin_bit_cast(s16x8, v);
    }
  }
  float bnH[2] = {bhh[c0[4] + l15], bhh[c0[5] + l15]};
  int len4[4];
#pragma unroll
  for (int r = 0; r < 4; r++) len4[r] = lenS[q * 4 + r];
  __syncthreads();
  const int maxlen = *mlS;

  float hold[2][4] = {{0, 0, 0, 0}, {0, 0, 0, 0}};  // fp32 recurrent carry
  const short qmask = (q < 2) ? (short)-1 : (short)0;
  const s16x8 qm = {qmask, qmask, qmask, qmask, qmask, qmask, qmask, qmask};

  for (int t = 0; t < maxlen; ++t) {
    __syncthreads();  // prev-iter h writes (and init) visible to all MFMA reads

    f32x4 acc[6];
#pragma unroll
    for (int i = 0; i < 6; i++) acc[i] = f32x4{0.f, 0.f, 0.f, 0.f};

    // aug kstep: acc = [state_t | 1] @ [Wih | bias]  (q>=2 lanes carry zeros)
    {
      s16x8 raw = *(const s16x8*)(SgL + t * 256 + ((q & 1) * 16 + l15) * 8);
      raw &= qm;
      b16x8 a8 = __builtin_bit_cast(b16x8, raw);
#pragma unroll
      for (int i = 0; i < 6; i++) acc[i] = mfma_bf16(a8, waugf[i], acc[i]);
    }
    f32x4 giN0 = acc[4], giN1 = acc[5];  // snapshot i_n (incl. bih fold)
    acc[4] = acc[4] + bnH[0];
    acc[5] = acc[5] + bnH[1];

    // resident h ksteps 0..5
#pragma unroll
    for (int j = 0; j < 6; j++) {
      b16x8 a = ld8(&Hb[l15 * 296 + j * 32 + q * 8]);
#pragma unroll
      for (int i = 0; i < 6; i++) acc[i] = mfma_bf16(a, wres[i][j], acc[i]);
    }
    // LDS-arena ksteps 6,7 (conflict-free per-lane slots)
#pragma unroll
    for (int ks2 = 0; ks2 < 2; ks2++) {
      b16x8 a = ld8(&Hb[l15 * 296 + (6 + ks2) * 32 + q * 8]);
#pragma unroll
      for (int i = 0; i < 6; i++) {
        b16x8 bw = ld8(W67L + (size_t)(ks2 * 6 + i) * 4096 + tid * 8);
        acc[i] = mfma_bf16(a, bw, acc[i]);
      }
    }
    __syncthreads();  // all reads of Hb done before overwrite

    // elementwise: acc elem = (row=q*4+rg, col=c0[i]+l15); biases pre-folded
#pragma unroll
    for (int i = 0; i < 2; i++) {
      const int c = 32 * w + 16 * i + l15;
#pragma unroll
      for (int rg = 0; rg < 4; rg++) {
        const int row = q * 4 + rg;
        float r = sigm(acc[0 + i][rg]);
        float z = sigm(acc[2 + i][rg]);
        float inn = i ? giN1[rg] : giN0[rg];
        float hn = acc[4 + i][rg] - inn;       // h_n = g_n - i_n
        float nn = tanh_fast(inn + r * hn);
        float hv = (1.f - z) * nn + z * hold[i][rg];
        hv = (t < len4[rg]) ? hv : hold[i][rg];  // ragged freeze
        hold[i][rg] = hv;
        Hb[row * 296 + c] = f2b(hv);
      }
    }
  }

  // emit x = [state[:,0,:], action, h, 0-pad] as bf16 [16][288]
#pragma unroll
  for (int i = 0; i < 2; i++) {
    const int c = 32 * w + 16 * i + l15;
#pragma unroll
    for (int rg = 0; rg < 4; rg++) {
      const int row = q * 4 + rg;
      xout[(size_t)(r0 + row) * 288 + 16 + c] = f2b(hold[i][rg]);
    }
  }
  {
    const int row = tid >> 5, cc = tid & 31;  // 512 threads cover 16x32
    float v; int col;
    if (cc < 15)       { v = state[(size_t)(r0 + row) * 960 + cc]; col = cc; }
    else if (cc == 15) { v = action[r0 + row]; col = 15; }
    else               { v = 0.f; col = 256 + cc; }  // 272..287 zero pad
    xout[(size_t)(r0 + row) * 288 + col] = f2b(v);
  }
}

// ---------- bf16 GEMM: Y = relu(A @ W^T + b); W is fp32, converted in staging ----
// BMxBN tile, 256 thr = 4 waves in 2x2; A bf16 [M][K], W fp32 [N][Ksrc], K padded.
template <int BM, int BN>
__global__ __launch_bounds__(256, 2) void gemm_bias_relu(
    const unsigned short* __restrict__ A0, const unsigned short* __restrict__ A1,
    const float* __restrict__ W0, const float* __restrict__ W1,
    const float* __restrict__ b0, const float* __restrict__ b1,
    unsigned short* __restrict__ Y0, unsigned short* __restrict__ Y1,
    int N, int K, int Ksrc) {
  const unsigned short* A = blockIdx.z ? A1 : A0;
  const float* W = blockIdx.z ? W1 : W0;
  const float* bias = blockIdx.z ? b1 : b0;
  unsigned short* Y = blockIdx.z ? Y1 : Y0;

  constexpr int MT = BM / 32;   // 16-row m-frags per wave
  constexpr int NT = BN / 32;   // 16-col n-frags per wave
  const int tid = threadIdx.x;
  const int lane = tid & 63, wid = tid >> 6;
  const int wm = wid >> 1, wn = wid & 1;
  const int l15 = lane & 15, q = lane >> 4;
  const int m0 = blockIdx.x * BM, n0 = blockIdx.y * BN;

  __shared__ unsigned short As[BM * 32];
  __shared__ unsigned short Bs[BN * 32];

  f32x4 acc[MT][NT];
#pragma unroll
  for (int mi = 0; mi < MT; mi++)
#pragma unroll
    for (int ni = 0; ni < NT; ni++) acc[mi][ni] = f32x4{0.f, 0.f, 0.f, 0.f};

  const int srow = tid >> 2, scol = (tid & 3) * 8;

  for (int k0 = 0; k0 < K; k0 += 32) {
#pragma unroll
    for (int g64 = 0; g64 < BM / 64; g64++)
      async16(A + (size_t)(m0 + g64 * 64 + srow) * K + scol + k0,
              &As[g64 * 2048 + tid * 8]);
#pragma unroll
    for (int g64 = 0; g64 < BN / 64; g64++) {
      const int wr = n0 + g64 * 64 + srow;
      const int k = k0 + scol;
      s16x8 h = {0, 0, 0, 0, 0, 0, 0, 0};
      if (k < Ksrc) {                       // 8-float groups never straddle Ksrc
        const float* wp = W + (size_t)wr * Ksrc + k;
        const float4 f0 = *(const float4*)wp;
        const float4 f1 = *(const float4*)(wp + 4);
        h[0] = (short)f2b(f0.x); h[1] = (short)f2b(f0.y);
        h[2] = (short)f2b(f0.z); h[3] = (short)f2b(f0.w);
        h[4] = (short)f2b(f1.x); h[5] = (short)f2b(f1.y);
        h[6] = (short)f2b(f1.z); h[7] = (short)f2b(f1.w);
      }
      *(s16x8*)&Bs[g64 * 2048 + tid * 8] = h;
    }
    __syncthreads();

    b16x8 af[MT], bf[NT];
#pragma unroll
    for (int mi = 0; mi < MT; mi++)
      af[mi] = ld8(&As[(wm * (BM / 2) + mi * 16 + l15) * 32 + q * 8]);
#pragma unroll
    for (int ni = 0; ni < NT; ni++)
      bf[ni] = ld8(&Bs[(wn * (BN / 2) + ni * 16 + l15) * 32 + q * 8]);
#pragma unroll
    for (int mi = 0; mi < MT; mi++)
#pragma unroll
      for (int ni = 0; ni < NT; ni++)
        acc[mi][ni] = mfma_bf16(af[mi], bf[ni], acc[mi][ni]);
    __syncthreads();
  }

#pragma unroll
  for (int ni = 0; ni < NT; ni++) {
    const int col = n0 + wn * (BN / 2) + ni * 16 + l15;
    const float bv = bias[col];
#pragma unroll
    for (int mi = 0; mi < MT; mi++) {
      const int rbase = m0 + wm * (BM / 2) + mi * 16 + q * 4;
#pragma unroll
      for (int rg = 0; rg < 4; rg++) {
        float v = acc[mi][ni][rg] + bv;
        v = fmaxf(v, 0.f);
        Y[(size_t)(rbase + rg) * N + col] = f2b(v);
      }
    }
  }
}

// ---------- final q-row: out[b] = y4[b,:] . qw + qb ----------
__global__ __launch_bounds__(256) void qdot(
    const unsigned short* __restrict__ y0, const unsigned short* __restrict__ y1,
    const float* __restrict__ qw0, const float* __restrict__ qb0,
    const float* __restrict__ qw1, const float* __restrict__ qb1,
    float* __restrict__ out) {
  const int lane = threadIdx.x & 63, wid = threadIdx.x >> 6;
  const int row = blockIdx.x * 4 + wid;
  const int br = blockIdx.y;
  const unsigned short* y = br ? y1 : y0;
  const float* qw = br ? qw1 : qw0;
  const float* qb = br ? qb1 : qb0;
  const unsigned short* p = y + (size_t)row * 256 + lane * 4;
  float s = 0.f;
#pragma unroll
  for (int j = 0; j < 4; j++) s += b2f(p[j]) * qw[lane * 4 + j];
#pragma unroll
  for (int off = 32; off > 0; off >>= 1) s += __shfl_down(s, off);
  if (lane == 0) out[br * 2048 + row] = s + qb[0];
}

// ---------- host ----------
extern "C" void kernel_launch(void* const* d_in, const int* in_sizes, int n_in,
                              void* d_out, int out_size, void* d_ws, size_t ws_size,
                              hipStream_t stream) {
  const float* state   = (const float*)d_in[0];
  const float* action  = (const float*)d_in[1];
  const int*   lengths = (const int*)d_in[2];
  const float* g_wih[2] = {(const float*)d_in[3], (const float*)d_in[17]};
  const float* g_whh[2] = {(const float*)d_in[4], (const float*)d_in[18]};
  const float* g_bih[2] = {(const float*)d_in[5], (const float*)d_in[19]};
  const float* g_bhh[2] = {(const float*)d_in[6], (const float*)d_in[20]};
  const float* fcw[2][4] = {
      {(const float*)d_in[7], (const float*)d_in[9], (const float*)d_in[11], (const float*)d_in[13]},
      {(const float*)d_in[21], (const float*)d_in[23], (const float*)d_in[25], (const float*)d_in[27]}};
  const float* fcb[2][4] = {
      {(const float*)d_in[8], (const float*)d_in[10], (const float*)d_in[12], (const float*)d_in[14]},
      {(const float*)d_in[22], (const float*)d_in[24], (const float*)d_in[26], (const float*)d_in[28]}};
  const float* qw[2] = {(const float*)d_in[15], (const float*)d_in[29]};
  const float* qb[2] = {(const float*)d_in[16], (const float*)d_in[30]};
  float* out = (float*)d_out;

  uintptr_t base = (uintptr_t)d_ws;
  auto alloc = [&](size_t bytes) -> unsigned short* {
    void* p = (void*)base;
    base += (bytes + 255) & ~(size_t)255;
    return (unsigned short*)p;
  };
  unsigned short *waug[2], *xb[2], *yA[2], *yB[2];
  for (int g = 0; g < 2; g++) waug[g] = alloc(768 * 288 * 2);
  for (int g = 0; g < 2; g++) xb[g] = alloc(2048 * 288 * 2);
  for (int g = 0; g < 2; g++) yA[g] = alloc(2048 * 1024 * 2);  // fc1 out; fc3 out reuses
  for (int g = 0; g < 2; g++) yB[g] = alloc(2048 * 1024 * 2);  // fc2 out; fc4 out reuses
  (void)ws_size; (void)in_sizes; (void)n_in; (void)out_size;

  prep_waug<<<dim3(32, 2), 256, 0, stream>>>(
      g_whh[0], g_wih[0], g_bih[0], g_bhh[0],
      g_whh[1], g_wih[1], g_bih[1], g_bhh[1], waug[0], waug[1]);

  static bool attr_done = false;   // idempotent attribute set (host-side, capture-safe)
  hipFuncSetAttribute((const void*)gru_kernel,
                      hipFuncAttributeMaxDynamicSharedMemorySize, GRU_LDS_BYTES);
  (void)attr_done;

  gru_kernel<<<dim3(256), dim3(512), GRU_LDS_BYTES, stream>>>(
      state, action, lengths, waug[0], waug[1], g_bhh[0], g_bhh[1], xb[0], xb[1]);

  gemm_bias_relu<64, 128><<<dim3(32, 8, 2), 256, 0, stream>>>(
      xb[0], xb[1], fcw[0][0], fcw[1][0], fcb[0][0], fcb[1][0], yA[0], yA[1],
      1024, 288, 272);
  gemm_bias_relu<64, 128><<<dim3(32, 8, 2), 256, 0, stream>>>(
      yA[0], yA[1], fcw[0][1], fcw[1][1], fcb[0][1], fcb[1][1], yB[0], yB[1],
      1024, 1024, 1024);
  gemm_bias_relu<64, 64><<<dim3(32, 8, 2), 256, 0, stream>>>(
      yB[0], yB[1], fcw[0][2], fcw[1][2], fcb[0][2], fcb[1][2], yA[0], yA[1],
      512, 1024, 1024);
  gemm_bias_relu<64, 64><<<dim3(32, 4, 2), 256, 0, stream>>>(
      yA[0], yA[1], fcw[0][3], fcw[1][3], fcb[0][3], fcb[1][3], yB[0], yB[1],
      256, 512, 512);

  qdot<<<dim3(512, 2), 256, 0, stream>>>(yB[0], yB[1], qw[0], qb[0], qw[1], qb[1], out);
}

// Round 4
// 336.782 us; speedup vs baseline: 1.5439x; 1.0568x over previous
//
#include <hip/hip_runtime.h>

// ---------- types ----------
typedef float  f32x4 __attribute__((ext_vector_type(4)));
typedef short  s16x8 __attribute__((ext_vector_type(8)));
typedef __bf16 b16x8 __attribute__((ext_vector_type(8)));

#define DEV __device__ __forceinline__

DEV unsigned short f2b(float f) {           // fp32 -> bf16 RNE
  unsigned u = __builtin_bit_cast(unsigned, f);
  u = (u + 0x7FFFu + ((u >> 16) & 1u)) >> 16;
  return (unsigned short)u;
}
DEV b16x8 ld8(const unsigned short* p) {    // 16B fragment load + reinterpret
  return __builtin_bit_cast(b16x8, *(const s16x8*)p);
}
DEV float sigm(float x) { return __builtin_amdgcn_rcpf(1.f + __expf(-x)); }
DEV float tanh_fast(float x) {
  float e = __expf(2.f * x);                // overflow-safe: e=inf -> 1, e=0 -> -1
  return 1.f - 2.f * __builtin_amdgcn_rcpf(e + 1.f);
}
DEV void async16(const unsigned short* g, unsigned short* l) {
  __builtin_amdgcn_global_load_lds(
      (const __attribute__((address_space(1))) unsigned int*)g,
      (__attribute__((address_space(3))) unsigned int*)l, 16, 0, 0);
}
DEV f32x4 mfma_bf16(b16x8 a, b16x8 b, f32x4 c) {
  return __builtin_amdgcn_mfma_f32_16x16x32_bf16(a, b, c, 0, 0, 0);
}

// ---------- prep: all fp32->bf16 weight conversion + Waug build + out prefill ----
// Waug [768][288] = [Whh k-permuted | Wih | bias@271 | 0].
// k-perm (storage k' < 256): within each 32-group, pos 32w+2t+s <- h-col 32w+t+16s,
// so the GRU's h-writes of (c, c+16) pairs are u32-contiguous.
struct PrepArgs {
  const float *whh[2], *wih[2], *bih[2], *bhh[2];
  const float *src[2][4];               // fc1..fc4 fp32 weights per branch
  unsigned short *waug[2], *dst[2][4];  // bf16 outputs
  const float *qb[2];
  float *out;                           // prefill with qb (fc4q atomically adds)
};

__global__ __launch_bounds__(256) void prep_kernel(PrepArgs p) {
  const int job = blockIdx.y;
  const int i0 = blockIdx.x * 256 + threadIdx.x;
  const int stride = gridDim.x * 256;
  if (job < 2) {
    const float* whh = p.whh[job];
    const float* wih = p.wih[job];
    const float* bih = p.bih[job];
    const float* bhh = p.bhh[job];
    unsigned short* dst = p.waug[job];
    for (int idx = i0; idx < 768 * 288; idx += stride) {
      int j = idx / 288, k = idx - j * 288;
      float v = 0.f;
      if (k < 256) {
        int o = k & 31;
        int kk = (k & 0x1E0) + (o >> 1) + ((o & 1) << 4);   // inverse pair-perm
        v = whh[j * 256 + kk];
      } else if (k < 271)  v = wih[j * 15 + (k - 256)];
      else if (k == 271)   v = (j < 512) ? (bih[j] + bhh[j]) : bih[j];
      dst[idx] = f2b(v);
    }
  } else if (job < 10) {
    const int jj = job - 2, br = jj >> 2, ly = jj & 3;
    const int rowsA[4] = {1024, 1024, 512, 256};
    const int scA[4]   = {272, 1024, 1024, 512};
    const int dcA[4]   = {288, 1024, 1024, 512};
    const float* src = p.src[br][ly];
    unsigned short* dst = p.dst[br][ly];
    const int sc = scA[ly], dc = dcA[ly], tot = rowsA[ly] * dc;
    for (int idx = i0; idx < tot; idx += stride) {
      int r = idx / dc, c = idx - r * dc;
      float v = (c < sc) ? src[r * sc + c] : 0.f;
      dst[idx] = f2b(v);
    }
  } else {
    for (int idx = i0; idx < 4096; idx += stride)
      p.out[idx] = p.qb[idx >> 11][0];
  }
}

// ---------- persistent fused GRU ----------
// 256 blocks x 512 thr; block = (gru g, 16 batch rows). Weights fully on-chip:
// ksteps {0..5, aug} in registers, {6,7} in per-lane LDS arena. Hb is
// double-buffered (ONE barrier/step) in XOR-swizzled 16B chunks; h written as
// packed b32 pairs (k-permuted Waug makes pairs contiguous).
#define GRU_LDS_BYTES 147584
__global__ __launch_bounds__(512) void gru_kernel(
    const float* __restrict__ state, const float* __restrict__ action,
    const int* __restrict__ lengths,
    const unsigned short* __restrict__ waug0, const unsigned short* __restrict__ waug1,
    const float* __restrict__ bhh0, const float* __restrict__ bhh1,
    unsigned short* __restrict__ x0, unsigned short* __restrict__ x1) {
  extern __shared__ char smem[];
  unsigned short* W67L = (unsigned short*)smem;             // 96 KB arena
  unsigned short* SgL  = (unsigned short*)(smem + 98304);   // 32 KB state frags
  unsigned*       Hb2  = (unsigned*)(smem + 131072);        // 2 x 16 x 128 dw
  int* lenS = (int*)(smem + 147456);
  int* mlS  = (int*)(smem + 147520);
  float* tmpF = (float*)smem;                               // phase-a overlay

  const int tid = threadIdx.x;
  const int lane = tid & 63, w = tid >> 6;
  const int l15 = lane & 15, q = lane >> 4;
  const int g = blockIdx.x & 1;
  const int r0 = (blockIdx.x >> 1) * 16;

  const unsigned short* Waug = g ? waug1 : waug0;
  const float* bhh = g ? bhh1 : bhh0;
  unsigned short* xout = g ? x1 : x0;

  // ---- phase a: state tile fp32 -> LDS (coalesced); lens; zero Hb ----
  {
    const float4* src = (const float4*)(state + (size_t)r0 * 960);
    float4* dstv = (float4*)tmpF;
    for (int i = tid; i < 3840; i += 512) dstv[i] = src[i];
  }
  for (int i = tid; i < 4096; i += 512) Hb2[i] = 0;
  if (tid < 16) lenS[tid] = lengths[r0 + tid];
  __syncthreads();
  if (tid == 0) {
    int m = 1;
    for (int i = 0; i < 16; i++) m = lenS[i] > m ? lenS[i] : m;
    *mlS = m;
  }

  // ---- phase b: SgL[t][L] = aug A-fragment (state 15 | 1.0 | 0) ----
  for (int s = tid; s < 64 * 32; s += 512) {
    const int t = s >> 5, L = s & 31;
    const int q2 = L >> 4, r = L & 15;
    s16x8 h;
#pragma unroll
    for (int j = 0; j < 8; j++) {
      const int k = q2 * 8 + j;
      float v = (k < 15) ? tmpF[r * 960 + t * 15 + k] : (k == 15 ? 1.0f : 0.f);
      h[j] = (short)f2b(v);
    }
    *(s16x8*)(SgL + (size_t)s * 8) = h;
  }
  __syncthreads();  // tmpF dead; arena may be filled

  // ---- phase c: resident weights + arena fill ----
  int c0[6];
  c0[0] = 32 * w;       c0[1] = 32 * w + 16;
  c0[2] = 256 + 32 * w; c0[3] = 256 + 32 * w + 16;
  c0[4] = 512 + 32 * w; c0[5] = 512 + 32 * w + 16;

  b16x8 wres[6][6];   // h ksteps 0..5
  b16x8 waugf[6];     // aug kstep
#pragma unroll
  for (int i = 0; i < 6; i++) {
    const unsigned short* bpi = Waug + (size_t)(c0[i] + l15) * 288 + q * 8;
#pragma unroll
    for (int j = 0; j < 6; j++) wres[i][j] = ld8(bpi + j * 32);
    waugf[i] = ld8(bpi + 256);
#pragma unroll
    for (int ks2 = 0; ks2 < 2; ks2++) {
      b16x8 v = ld8(bpi + (6 + ks2) * 32);
      *(s16x8*)(W67L + (size_t)(ks2 * 6 + i) * 4096 + tid * 8) =
          __builtin_bit_cast(s16x8, v);
    }
  }
  float bnH[2] = {bhh[c0[4] + l15], bhh[c0[5] + l15]};
  int len4[4];
#pragma unroll
  for (int r = 0; r < 4; r++) len4[r] = lenS[q * 4 + r];

  // A-frag read offsets (dwords): row=l15, chunk 4j+q, XOR-swizzle by row&7
  int aOff[8];
#pragma unroll
  for (int j = 0; j < 8; j++) {
    const int cj = 4 * j + q;
    const int pj = (cj & 24) | ((cj & 7) ^ (l15 & 7));
    aOff[j] = l15 * 128 + pj * 4;
  }
  // h-pair write offsets (dwords): row=q*4+rg, dw idx 16w+l15
  int wOff[4];
#pragma unroll
  for (int rg = 0; rg < 4; rg++) {
    const int row = q * 4 + rg;
    const int cb = 4 * w + (l15 >> 2);
    const int pw = (cb & 24) | ((cb & 7) ^ (row & 7));
    wOff[rg] = row * 128 + pw * 4 + (l15 & 3);
  }
  __syncthreads();
  const int maxlen = *mlS;

  float hold[2][4] = {{0, 0, 0, 0}, {0, 0, 0, 0}};
  const short qmask = (q < 2) ? (short)-1 : (short)0;
  const s16x8 qm = {qmask, qmask, qmask, qmask, qmask, qmask, qmask, qmask};
  int poff = 0;  // read-buffer dword offset (0 / 2048)

  for (int t = 0; t < maxlen; ++t) {
    __syncthreads();  // prev step's writes to buffer poff complete

    f32x4 acc[6];
#pragma unroll
    for (int i = 0; i < 6; i++) acc[i] = f32x4{0.f, 0.f, 0.f, 0.f};

    // aug kstep: [state_t | 1] @ [Wih | bias]
    {
      s16x8 raw = *(const s16x8*)(SgL + t * 256 + ((q & 1) * 16 + l15) * 8);
      raw &= qm;
      b16x8 a8 = __builtin_bit_cast(b16x8, raw);
#pragma unroll
      for (int i = 0; i < 6; i++) acc[i] = mfma_bf16(a8, waugf[i], acc[i]);
    }
    f32x4 giN0 = acc[4], giN1 = acc[5];  // i_n snapshot
    acc[4] = acc[4] + bnH[0];
    acc[5] = acc[5] + bnH[1];

    const unsigned* hb = Hb2 + poff;
    // resident h ksteps 0..5
#pragma unroll
    for (int j = 0; j < 6; j++) {
      b16x8 a = __builtin_bit_cast(b16x8, *(const uint4*)(hb + aOff[j]));
#pragma unroll
      for (int i = 0; i < 6; i++) acc[i] = mfma_bf16(a, wres[i][j], acc[i]);
    }
    // arena ksteps 6,7
#pragma unroll
    for (int ks2 = 0; ks2 < 2; ks2++) {
      b16x8 a = __builtin_bit_cast(b16x8, *(const uint4*)(hb + aOff[6 + ks2]));
#pragma unroll
      for (int i = 0; i < 6; i++) {
        b16x8 bw = ld8(W67L + (size_t)(ks2 * 6 + i) * 4096 + tid * 8);
        acc[i] = mfma_bf16(a, bw, acc[i]);
      }
    }

    // elementwise + packed write to the OTHER buffer (no second barrier)
    unsigned* hbw = Hb2 + (poff ^ 2048);
#pragma unroll
    for (int rg = 0; rg < 4; rg++) {
      const bool live = (t < len4[rg]);
      float r0g = sigm(acc[0][rg]);
      float z0 = sigm(acc[2][rg]);
      float n0 = tanh_fast(giN0[rg] + r0g * (acc[4][rg] - giN0[rg]));
      float h0 = n0 + z0 * (hold[0][rg] - n0);
      h0 = live ? h0 : hold[0][rg];
      hold[0][rg] = h0;
      float r1g = sigm(acc[1][rg]);
      float z1 = sigm(acc[3][rg]);
      float n1 = tanh_fast(giN1[rg] + r1g * (acc[5][rg] - giN1[rg]));
      float h1 = n1 + z1 * (hold[1][rg] - n1);
      h1 = live ? h1 : hold[1][rg];
      hold[1][rg] = h1;
      hbw[wOff[rg]] = (unsigned)f2b(h0) | ((unsigned)f2b(h1) << 16);
    }
    poff ^= 2048;
  }

  // emit x = [state[:,0,:], action, h, 0-pad] bf16 [16][288]
#pragma unroll
  for (int i = 0; i < 2; i++) {
    const int c = 32 * w + 16 * i + l15;
#pragma unroll
    for (int rg = 0; rg < 4; rg++) {
      const int row = q * 4 + rg;
      xout[(size_t)(r0 + row) * 288 + 16 + c] = f2b(hold[i][rg]);
    }
  }
  {
    const int row = tid >> 5, cc = tid & 31;
    float v; int col;
    if (cc < 15)       { v = state[(size_t)(r0 + row) * 960 + cc]; col = cc; }
    else if (cc == 15) { v = action[r0 + row]; col = 15; }
    else               { v = 0.f; col = 256 + cc; }  // 272..287 zero pad
    xout[(size_t)(r0 + row) * 288 + col] = f2b(v);
  }
}

// ---------- bf16 GEMM: Y = relu(A @ W^T + b); both operands bf16, async16 ----
template <int BM, int BN>
__global__ __launch_bounds__(256, 2) void gemm_bias_relu(
    const unsigned short* __restrict__ A0, const unsigned short* __restrict__ A1,
    const unsigned short* __restrict__ W0, const unsigned short* __restrict__ W1,
    const float* __restrict__ b0, const float* __restrict__ b1,
    unsigned short* __restrict__ Y0, unsigned short* __restrict__ Y1,
    int N, int K) {
  const unsigned short* A = blockIdx.z ? A1 : A0;
  const unsigned short* W = blockIdx.z ? W1 : W0;
  const float* bias = blockIdx.z ? b1 : b0;
  unsigned short* Y = blockIdx.z ? Y1 : Y0;

  constexpr int MT = BM / 32;
  constexpr int NT = BN / 32;
  const int tid = threadIdx.x;
  const int lane = tid & 63, wid = tid >> 6;
  const int wm = wid >> 1, wn = wid & 1;
  const int l15 = lane & 15, q = lane >> 4;
  const int m0 = blockIdx.x * BM, n0 = blockIdx.y * BN;

  __shared__ unsigned short As[BM * 32];
  __shared__ unsigned short Bs[BN * 32];

  f32x4 acc[MT][NT];
#pragma unroll
  for (int mi = 0; mi < MT; mi++)
#pragma unroll
    for (int ni = 0; ni < NT; ni++) acc[mi][ni] = f32x4{0.f, 0.f, 0.f, 0.f};

  const int srow = tid >> 2, scol = (tid & 3) * 8;

  for (int k0 = 0; k0 < K; k0 += 32) {
#pragma unroll
    for (int g64 = 0; g64 < BM / 64; g64++)
      async16(A + (size_t)(m0 + g64 * 64 + srow) * K + scol + k0,
              &As[g64 * 2048 + tid * 8]);
#pragma unroll
    for (int g64 = 0; g64 < BN / 64; g64++)
      async16(W + (size_t)(n0 + g64 * 64 + srow) * K + scol + k0,
              &Bs[g64 * 2048 + tid * 8]);
    __syncthreads();

    b16x8 af[MT], bf[NT];
#pragma unroll
    for (int mi = 0; mi < MT; mi++)
      af[mi] = ld8(&As[(wm * (BM / 2) + mi * 16 + l15) * 32 + q * 8]);
#pragma unroll
    for (int ni = 0; ni < NT; ni++)
      bf[ni] = ld8(&Bs[(wn * (BN / 2) + ni * 16 + l15) * 32 + q * 8]);
#pragma unroll
    for (int mi = 0; mi < MT; mi++)
#pragma unroll
      for (int ni = 0; ni < NT; ni++)
        acc[mi][ni] = mfma_bf16(af[mi], bf[ni], acc[mi][ni]);
    __syncthreads();
  }

#pragma unroll
  for (int ni = 0; ni < NT; ni++) {
    const int col = n0 + wn * (BN / 2) + ni * 16 + l15;
    const float bv = bias[col];
#pragma unroll
    for (int mi = 0; mi < MT; mi++) {
      const int rbase = m0 + wm * (BM / 2) + mi * 16 + q * 4;
#pragma unroll
      for (int rg = 0; rg < 4; rg++) {
        float v = acc[mi][ni][rg] + bv;
        v = fmaxf(v, 0.f);
        Y[(size_t)(rbase + rg) * N + col] = f2b(v);
      }
    }
  }
}

// ---------- fc4 + q fused: out[b] += qw . relu(y3[b] @ W4^T + b4) ----------
// BM=32, BN=128 n-half via blockIdx.y; atomicAdd into qb-prefilled out.
__global__ __launch_bounds__(256, 2) void fc4q_kernel(
    const unsigned short* __restrict__ A0, const unsigned short* __restrict__ A1,
    const unsigned short* __restrict__ W0, const unsigned short* __restrict__ W1,
    const float* __restrict__ b0, const float* __restrict__ b1,
    const float* __restrict__ qw0, const float* __restrict__ qw1,
    float* __restrict__ out) {
  const unsigned short* A = blockIdx.z ? A1 : A0;
  const unsigned short* W = blockIdx.z ? W1 : W0;
  const float* bias = blockIdx.z ? b1 : b0;
  const float* qw = blockIdx.z ? qw1 : qw0;

  const int tid = threadIdx.x;
  const int lane = tid & 63, wn = tid >> 6;      // 4 waves = 4 n-quarters
  const int l15 = lane & 15, q = lane >> 4;
  const int m0 = blockIdx.x * 32;
  const int nbase = blockIdx.y * 128;            // n-half
  const int K = 512;

  __shared__ unsigned short As[32 * 32];
  __shared__ unsigned short Bs[128 * 32];
  __shared__ float red[32][4];

  f32x4 acc[2][2];
#pragma unroll
  for (int mi = 0; mi < 2; mi++)
#pragma unroll
    for (int ni = 0; ni < 2; ni++) acc[mi][ni] = f32x4{0.f, 0.f, 0.f, 0.f};

  const int srow = tid >> 2, scol = (tid & 3) * 8;
  for (int k0 = 0; k0 < K; k0 += 32) {
    if (tid < 128)
      async16(A + (size_t)(m0 + srow) * K + scol + k0, &As[tid * 8]);
#pragma unroll
    for (int g64 = 0; g64 < 2; g64++)
      async16(W + (size_t)(nbase + g64 * 64 + srow) * K + scol + k0,
              &Bs[g64 * 2048 + tid * 8]);
    __syncthreads();

    b16x8 af[2], bf[2];
#pragma unroll
    for (int mi = 0; mi < 2; mi++)
      af[mi] = ld8(&As[(mi * 16 + l15) * 32 + q * 8]);
#pragma unroll
    for (int ni = 0; ni < 2; ni++)
      bf[ni] = ld8(&Bs[(wn * 32 + ni * 16 + l15) * 32 + q * 8]);
#pragma unroll
    for (int mi = 0; mi < 2; mi++)
#pragma unroll
      for (int ni = 0; ni < 2; ni++)
        acc[mi][ni] = mfma_bf16(af[mi], bf[ni], acc[mi][ni]);
    __syncthreads();
  }

  // partial q-dot over this wave's 32 cols
#pragma unroll
  for (int mi = 0; mi < 2; mi++) {
#pragma unroll
    for (int rg = 0; rg < 4; rg++) {
      float s = 0.f;
#pragma unroll
      for (int ni = 0; ni < 2; ni++) {
        const int col = nbase + wn * 32 + ni * 16 + l15;
        float v = fmaxf(acc[mi][ni][rg] + bias[col], 0.f);
        s += v * qw[col];
      }
#pragma unroll
      for (int off = 1; off < 16; off <<= 1) s += __shfl_xor(s, off);
      if (l15 == 0) red[mi * 16 + q * 4 + rg][wn] = s;
    }
  }
  __syncthreads();
  if (tid < 32) {
    float t = red[tid][0] + red[tid][1] + red[tid][2] + red[tid][3];
    atomicAdd(out + (size_t)blockIdx.z * 2048 + m0 + tid, t);
  }
}

// ---------- host ----------
extern "C" void kernel_launch(void* const* d_in, const int* in_sizes, int n_in,
                              void* d_out, int out_size, void* d_ws, size_t ws_size,
                              hipStream_t stream) {
  const float* state   = (const float*)d_in[0];
  const float* action  = (const float*)d_in[1];
  const int*   lengths = (const int*)d_in[2];
  const float* g_wih[2] = {(const float*)d_in[3], (const float*)d_in[17]};
  const float* g_whh[2] = {(const float*)d_in[4], (const float*)d_in[18]};
  const float* g_bih[2] = {(const float*)d_in[5], (const float*)d_in[19]};
  const float* g_bhh[2] = {(const float*)d_in[6], (const float*)d_in[20]};
  const float* fcw[2][4] = {
      {(const float*)d_in[7], (const float*)d_in[9], (const float*)d_in[11], (const float*)d_in[13]},
      {(const float*)d_in[21], (const float*)d_in[23], (const float*)d_in[25], (const float*)d_in[27]}};
  const float* fcb[2][4] = {
      {(const float*)d_in[8], (const float*)d_in[10], (const float*)d_in[12], (const float*)d_in[14]},
      {(const float*)d_in[22], (const float*)d_in[24], (const float*)d_in[26], (const float*)d_in[28]}};
  const float* qw[2] = {(const float*)d_in[15], (const float*)d_in[29]};
  const float* qb[2] = {(const float*)d_in[16], (const float*)d_in[30]};
  float* out = (float*)d_out;

  uintptr_t base = (uintptr_t)d_ws;
  auto alloc = [&](size_t bytes) -> unsigned short* {
    void* p = (void*)base;
    base += (bytes + 255) & ~(size_t)255;
    return (unsigned short*)p;
  };
  unsigned short *waug[2], *w1b[2], *w2b[2], *w3b[2], *w4b[2], *xb[2], *yA[2], *yB[2];
  for (int g = 0; g < 2; g++) waug[g] = alloc(768 * 288 * 2);
  for (int g = 0; g < 2; g++) w1b[g] = alloc(1024 * 288 * 2);
  for (int g = 0; g < 2; g++) w2b[g] = alloc(1024 * 1024 * 2);
  for (int g = 0; g < 2; g++) w3b[g] = alloc(512 * 1024 * 2);
  for (int g = 0; g < 2; g++) w4b[g] = alloc(256 * 512 * 2);
  for (int g = 0; g < 2; g++) xb[g] = alloc(2048 * 288 * 2);
  for (int g = 0; g < 2; g++) yA[g] = alloc(2048 * 1024 * 2);
  for (int g = 0; g < 2; g++) yB[g] = alloc(2048 * 1024 * 2);
  (void)ws_size; (void)in_sizes; (void)n_in; (void)out_size;

  PrepArgs pa;
  for (int g = 0; g < 2; g++) {
    pa.whh[g] = g_whh[g]; pa.wih[g] = g_wih[g];
    pa.bih[g] = g_bih[g]; pa.bhh[g] = g_bhh[g];
    pa.waug[g] = waug[g];
    pa.src[g][0] = fcw[g][0]; pa.dst[g][0] = w1b[g];
    pa.src[g][1] = fcw[g][1]; pa.dst[g][1] = w2b[g];
    pa.src[g][2] = fcw[g][2]; pa.dst[g][2] = w3b[g];
    pa.src[g][3] = fcw[g][3]; pa.dst[g][3] = w4b[g];
    pa.qb[g] = qb[g];
  }
  pa.out = out;
  prep_kernel<<<dim3(64, 11), 256, 0, stream>>>(pa);

  (void)hipFuncSetAttribute((const void*)gru_kernel,
                            hipFuncAttributeMaxDynamicSharedMemorySize,
                            GRU_LDS_BYTES);
  gru_kernel<<<dim3(256), dim3(512), GRU_LDS_BYTES, stream>>>(
      state, action, lengths, waug[0], waug[1], g_bhh[0], g_bhh[1], xb[0], xb[1]);

  gemm_bias_relu<128, 128><<<dim3(16, 8, 2), 256, 0, stream>>>(
      xb[0], xb[1], w1b[0], w1b[1], fcb[0][0], fcb[1][0], yA[0], yA[1], 1024, 288);
  gemm_bias_relu<128, 128><<<dim3(16, 8, 2), 256, 0, stream>>>(
      yA[0], yA[1], w2b[0], w2b[1], fcb[0][1], fcb[1][1], yB[0], yB[1], 1024, 1024);
  gemm_bias_relu<128, 64><<<dim3(16, 8, 2), 256, 0, stream>>>(
      yB[0], yB[1], w3b[0], w3b[1], fcb[0][2], fcb[1][2], yA[0], yA[1], 512, 1024);
  fc4q_kernel<<<dim3(64, 2, 2), 256, 0, stream>>>(
      yA[0], yA[1], w4b[0], w4b[1], fcb[0][3], fcb[1][3], qw[0], qw[1], out);
}